// Round 6
// baseline (788.299 us; speedup 1.0000x reference)
//
#include <hip/hip_runtime.h>
#include <cstdint>
#include <cstddef>

// GraphMambaLayer on MI355X.
// R6: piw/ffn1 (N=2048, K=512) moved to a 256x256-tile 8-phase counted-vmcnt
// GEMM (8 waves, BK=64, 128KiB dyn LDS, vmcnt(4)@P4/P8, setprio around MFMA).
// Staging ledger (per iteration j, buffers static: b0=even ktile, b1=odd):
//   P1: stage Ah0(b1,2j+1)  P2: Ah1(b1,2j+1)   [b1 A-reads ended prev P7]
//   P3: Bh0(b0,2j+2)        P4: Bh1(b0,2j+2)   [b0 B-reads ended P2]
//   P5: Ah0(b0,2j+2)        P6: Ah1(b0,2j+2)   [b0 A-reads ended P3]
//   P7: Bh0(b1,2j+3)        P8: Bh1(b1,2j+3)   [b1 B-reads ended P6]
// vmcnt(4) end-P4: drains P7,P8,P1,P2 (8 oldest of 12) = b1 complete before P5.
// vmcnt(4) end-P8: drains P3..P6 = b0 complete before next P1. Last iter: vmcnt(0)@P4.
// R5: 754 us absmax 0.0625. R4: 832. R3: 928.

typedef unsigned short u16;
typedef __bf16 bf16x8 __attribute__((ext_vector_type(8)));
typedef float f32x4 __attribute__((ext_vector_type(4)));

#define MROWS 8192

__device__ __forceinline__ u16 f2bf(float f){
  unsigned u = __float_as_uint(f);
  u += 0x7FFFu + ((u >> 16) & 1u);           // RNE
  return (u16)(u >> 16);
}
__device__ __forceinline__ float bf2f(u16 v){
  return __uint_as_float((unsigned)v << 16);
}

__device__ __forceinline__ float wred64(float v){
#pragma unroll
  for (int o = 32; o > 0; o >>= 1) v += __shfl_xor(v, o, 64);
  return v;
}

#define GLD16(gp, lp) __builtin_amdgcn_global_load_lds( \
    (const __attribute__((address_space(1))) unsigned int*)(gp), \
    (__attribute__((address_space(3))) unsigned int*)(lp), 16, 0, 0)

#define BARRIER() do { asm volatile("" ::: "memory"); \
  __builtin_amdgcn_s_barrier(); asm volatile("" ::: "memory"); } while(0)
#define VMW(n) asm volatile("s_waitcnt vmcnt(" #n ")" ::: "memory")
#define LGKM0() asm volatile("s_waitcnt lgkmcnt(0)" ::: "memory")

// ---------------- merged weight transpose + bf16 convert ---------------------
struct TDesc { const float* src; u16* dst; int R, Kpad, C, zgate, nbx, base; };
struct TPack { TDesc d[16]; };

__global__ __launch_bounds__(256) void transpose_all(TPack p){
  int bid = blockIdx.x;
  TDesc dd = p.d[0];
#pragma unroll
  for (int i = 1; i < 16; ++i) if (bid >= p.d[i].base) dd = p.d[i];
  int lb = bid - dd.base;
  int bx = lb % dd.nbx, by = lb / dd.nbx;

  __shared__ float tile[32][33];
  int n0 = bx << 5, k0 = by << 5;
  int tx = threadIdx.x & 31, ty = threadIdx.x >> 5;
#pragma unroll
  for (int i = 0; i < 32; i += 8){
    int k = k0 + ty + i, n = n0 + tx;
    int oc = n;
    if (dd.zgate){ int g = n >> 5, sl = n & 31;
      oc = (sl < 16) ? (g << 4) + sl : (dd.C >> 1) + (g << 4) + sl - 16; }
    tile[ty + i][tx] = (k < dd.R) ? dd.src[(size_t)k * dd.C + oc] : 0.f;
  }
  __syncthreads();
#pragma unroll
  for (int i = 0; i < 32; i += 8){
    int n = n0 + ty + i, k = k0 + tx;
    dd.dst[(size_t)n * dd.Kpad + k] = f2bf(tile[tx][ty + i]);
  }
}

// ---------------- attn_maps moments -> sinusoidal encoding -------------------
__global__ __launch_bounds__(256) void stats_enc(
    const float* __restrict__ attn, u16* __restrict__ enc){
  int row = blockIdx.x;
  const float4* a4 = (const float4*)(attn + (size_t)row * 4096);
  int t = threadIdx.x;
  const float inv63 = 1.0f / 63.0f;
  float s0 = 0, sy = 0, sx = 0, sy2 = 0, sx2 = 0;
#pragma unroll
  for (int i = 0; i < 4; ++i){
    int c = t + 256 * i;
    float4 v = a4[c];
    int n = 4 * c;
#pragma unroll
    for (int e = 0; e < 4; ++e){
      float av = (&v.x)[e];
      int nn = n + e;
      float gy = (float)(nn >> 6) * inv63;
      float gx = (float)(nn & 63) * inv63;
      s0 += av; sy += av * gy; sx += av * gx;
      sy2 += av * gy * gy; sx2 += av * gx * gx;
    }
  }
  s0 = wred64(s0); sy = wred64(sy); sx = wred64(sx);
  sy2 = wred64(sy2); sx2 = wred64(sx2);
  __shared__ float red[4][5];
  __shared__ float outv[3];
  int wv = t >> 6, lane = t & 63;
  if (lane == 0){ red[wv][0]=s0; red[wv][1]=sy; red[wv][2]=sx; red[wv][3]=sy2; red[wv][4]=sx2; }
  __syncthreads();
  if (t == 0){
    float S=0, Ay=0, Ax=0, Ay2=0, Ax2=0;
    for (int w = 0; w < 4; ++w){ S+=red[w][0]; Ay+=red[w][1]; Ax+=red[w][2]; Ay2+=red[w][3]; Ax2+=red[w][4]; }
    float denom = S + 1e-8f;
    float cy = Ay / denom, cx = Ax / denom;
    float sp2 = (Ay2 - 2.f*cy*Ay + cy*cy*S + Ax2 - 2.f*cx*Ax + cx*cx*S) / denom;
    outv[0] = cy; outv[1] = cx; outv[2] = sqrtf(fmaxf(sp2, 0.f));
  }
  __syncthreads();
  if (t < 192){
    float cy = outv[0], cx = outv[1];
    float val = 0.f;
    if (t < 128){
      int j = t & 31;
      float fr = expf(-0.28782313662425572f * (float)j);   // ln(10000)/32
      float base = (t < 64) ? cy : cx;
      float ang = base * fr;
      val = ((t >> 5) & 1) ? cosf(ang) : sinf(ang);
    } else if (t == 128) val = outv[2];
    enc[(size_t)row * 192 + t] = f2bf(val);
  }
}

// ---------------- LayerNorm kernels (1 wave / row) ---------------------------
__global__ __launch_bounds__(256) void ln_dual(
    const float* __restrict__ x,
    const float* __restrict__ g1, const float* __restrict__ b1,
    const float* __restrict__ g2, const float* __restrict__ b2,
    u16* __restrict__ o1, u16* __restrict__ o2){
  int row = blockIdx.x * 4 + (threadIdx.x >> 6);
  int lane = threadIdx.x & 63, c = lane * 8;
  const float* xr = x + (size_t)row * 512 + c;
  float v[8];
  *(float4*)(v) = *(const float4*)(xr); *(float4*)(v+4) = *(const float4*)(xr+4);
  float s = 0.f;
#pragma unroll
  for (int j = 0; j < 8; ++j) s += v[j];
  float m = wred64(s) * (1.f/512.f);
  float q = 0.f;
#pragma unroll
  for (int j = 0; j < 8; ++j){ float d = v[j]-m; q += d*d; }
  float rstd = rsqrtf(wred64(q)*(1.f/512.f) + 1e-5f);
  float G1[8],B1[8],G2[8],B2[8];
  *(float4*)(G1)=*(const float4*)(g1+c); *(float4*)(G1+4)=*(const float4*)(g1+c+4);
  *(float4*)(B1)=*(const float4*)(b1+c); *(float4*)(B1+4)=*(const float4*)(b1+c+4);
  *(float4*)(G2)=*(const float4*)(g2+c); *(float4*)(G2+4)=*(const float4*)(g2+c+4);
  *(float4*)(B2)=*(const float4*)(b2+c); *(float4*)(B2+4)=*(const float4*)(b2+c+4);
  u16 u1[8] __attribute__((aligned(16)));
  u16 u2[8] __attribute__((aligned(16)));
#pragma unroll
  for (int j = 0; j < 8; ++j){
    float nv = (v[j]-m)*rstd;
    u1[j] = f2bf(nv*G1[j]+B1[j]);
    u2[j] = f2bf(nv*G2[j]+B2[j]);
  }
  *(uint4*)(o1 + (size_t)row*512 + c) = *(const uint4*)u1;
  *(uint4*)(o2 + (size_t)row*512 + c) = *(const uint4*)u2;
}

// bf16 in -> bf16 out LN over 1024; 16384 stacked rows, params per row-half
__global__ __launch_bounds__(256) void ln1024(
    const u16* __restrict__ x,
    const float* __restrict__ gf, const float* __restrict__ bfp,
    const float* __restrict__ gb, const float* __restrict__ bbp,
    u16* __restrict__ o){
  int row = blockIdx.x * 4 + (threadIdx.x >> 6);
  int lane = threadIdx.x & 63, c = lane * 16;
  const float* g = (row >> 13) ? gb : gf;
  const float* b = (row >> 13) ? bbp : bfp;
  const u16* xr = x + (size_t)row * 1024 + c;
  u16 raw[16] __attribute__((aligned(16)));
  *(uint4*)(raw)     = *(const uint4*)(xr);
  *(uint4*)(raw + 8) = *(const uint4*)(xr + 8);
  float v[16];
#pragma unroll
  for (int j = 0; j < 16; ++j) v[j] = bf2f(raw[j]);
  float s = 0.f;
#pragma unroll
  for (int j = 0; j < 16; ++j) s += v[j];
  float m = wred64(s) * (1.f/1024.f);
  float q = 0.f;
#pragma unroll
  for (int j = 0; j < 16; ++j){ float d = v[j]-m; q += d*d; }
  float rstd = rsqrtf(wred64(q)*(1.f/1024.f) + 1e-5f);
  float G[16], B[16];
#pragma unroll
  for (int i = 0; i < 4; ++i){
    *(float4*)(G + 4*i) = *(const float4*)(g + c + 4*i);
    *(float4*)(B + 4*i) = *(const float4*)(b + c + 4*i);
  }
  u16 u[16] __attribute__((aligned(16)));
#pragma unroll
  for (int j = 0; j < 16; ++j) u[j] = f2bf((v[j]-m)*rstd*G[j] + B[j]);
  *(uint4*)(o + (size_t)row*1024 + c)     = *(const uint4*)(u);
  *(uint4*)(o + (size_t)row*1024 + c + 8) = *(const uint4*)(u + 8);
}

// r2(bf16) -> s1 = LN(r2; ng,nb) (bf16), h2 = LN(s1; fg,fb) (bf16)
__global__ __launch_bounds__(256) void ln_double(
    const u16* __restrict__ x,
    const float* __restrict__ ng, const float* __restrict__ nb,
    const float* __restrict__ fg, const float* __restrict__ fbv,
    u16* __restrict__ s1, u16* __restrict__ h2){
  int row = blockIdx.x * 4 + (threadIdx.x >> 6);
  int lane = threadIdx.x & 63, c = lane * 8;
  const u16* xr = x + (size_t)row * 512 + c;
  u16 raw[8] __attribute__((aligned(16)));
  *(uint4*)(raw) = *(const uint4*)(xr);
  float v[8];
#pragma unroll
  for (int j = 0; j < 8; ++j) v[j] = bf2f(raw[j]);
  float s = 0.f;
#pragma unroll
  for (int j = 0; j < 8; ++j) s += v[j];
  float m = wred64(s) * (1.f/512.f);
  float q = 0.f;
#pragma unroll
  for (int j = 0; j < 8; ++j){ float d = v[j]-m; q += d*d; }
  float rstd = rsqrtf(wred64(q)*(1.f/512.f) + 1e-5f);
  float NG[8],NB[8],FG[8],FB[8];
  *(float4*)(NG)=*(const float4*)(ng+c); *(float4*)(NG+4)=*(const float4*)(ng+c+4);
  *(float4*)(NB)=*(const float4*)(nb+c); *(float4*)(NB+4)=*(const float4*)(nb+c+4);
  *(float4*)(FG)=*(const float4*)(fg+c); *(float4*)(FG+4)=*(const float4*)(fg+c+4);
  *(float4*)(FB)=*(const float4*)(fbv+c);*(float4*)(FB+4)=*(const float4*)(fbv+c+4);
  float w[8];
#pragma unroll
  for (int j = 0; j < 8; ++j) w[j] = (v[j]-m)*rstd*NG[j] + NB[j];
  u16 us[8] __attribute__((aligned(16)));
#pragma unroll
  for (int j = 0; j < 8; ++j) us[j] = f2bf(w[j]);
  *(uint4*)(s1 + (size_t)row*512 + c) = *(const uint4*)us;
  float s2 = 0.f;
#pragma unroll
  for (int j = 0; j < 8; ++j) s2 += w[j];
  float m2 = wred64(s2) * (1.f/512.f);
  float q2 = 0.f;
#pragma unroll
  for (int j = 0; j < 8; ++j){ float d = w[j]-m2; q2 += d*d; }
  float rstd2 = rsqrtf(wred64(q2)*(1.f/512.f) + 1e-5f);
  u16 u[8] __attribute__((aligned(16)));
#pragma unroll
  for (int j = 0; j < 8; ++j) u[j] = f2bf((w[j]-m2)*rstd2*FG[j] + FB[j]);
  *(uint4*)(h2 + (size_t)row*512 + c) = *(const uint4*)u;
}

// ---------------- 128-wide BN GEMM (N=512 shapes), proven m97 structure ------
// EPI 0: bf16 out = gelu(v+bias)                    (ldo = N)
// EPI 1: f32 out = v+bias+res_f32                   (ldo = N)
// EPI 2: f32 out = (v+bias+res_bf16)*km[row]        (ldo = N)
// EPI 4: bf16 out[(row&8191)*ldo + (row>>13)*512 + col] = v+bias+res_f32
template<int EPI, int BM>
__global__ __launch_bounds__(256, (BM == 64) ? 4 : 2) void gemm_bt(
    const u16* __restrict__ A,
    const u16* __restrict__ BT0, const u16* __restrict__ BT1,
    const float* __restrict__ bias0, const float* __restrict__ bias1,
    const void* __restrict__ res,
    float* __restrict__ outF, u16* __restrict__ outB,
    const float* __restrict__ km,
    int K, int N, int ldo){
  constexpr int MR = BM / 32;
  __shared__ u16 Asm[BM * 64];
  __shared__ u16 Bsm[128 * 64];
  const int tid = threadIdx.x, wv = tid >> 6, lane = tid & 63;
  const int m0 = blockIdx.y * BM, n0 = blockIdx.x << 7;
  const int wr = wv >> 1, wc = wv & 1;
  const u16* BT = (m0 < MROWS) ? BT0 : BT1;
  const float* bias = (m0 < MROWS) ? bias0 : bias1;

  const int rowin = lane >> 3;
  const int ksrc = ((16 * (lane & 7)) ^ (rowin << 4)) >> 1;
  const int rA = wv * (BM / 4) + rowin;
  const int rB = (wv << 5) + rowin;
  const u16* gA = A + (size_t)(m0 + rA) * K + ksrc;
  const u16* gB = BT + (size_t)(n0 + rB) * K + ksrc;
  u16* ldsA = Asm + wv * (BM / 4) * 64;
  u16* ldsB = Bsm + (wv << 11);

  f32x4 acc[MR][4] = {};
  const int cbase = 16 * (lane >> 4);
  const int swz = (lane & 7) << 4;

  for (int kt = 0; kt < K; kt += 64){
#pragma unroll
    for (int it = 0; it < BM / 32; ++it)
      GLD16(gA + (size_t)it * 8 * K + kt, ldsA + it * 512);
#pragma unroll
    for (int it = 0; it < 4; ++it)
      GLD16(gB + (size_t)it * 8 * K + kt, ldsB + it * 512);
    __syncthreads();
#pragma unroll
    for (int ks = 0; ks < 64; ks += 32){
      const int cs = ((2 * ks + cbase) ^ swz) >> 1;
      bf16x8 af[MR], bfr[4];
#pragma unroll
      for (int m = 0; m < MR; ++m)
        af[m] = *reinterpret_cast<const bf16x8*>(&Asm[(wr*(BM/2) + m*16 + (lane & 15)) * 64 + cs]);
#pragma unroll
      for (int n = 0; n < 4; ++n)
        bfr[n] = *reinterpret_cast<const bf16x8*>(&Bsm[(wc*64 + n*16 + (lane & 15)) * 64 + cs]);
#pragma unroll
      for (int m = 0; m < MR; ++m)
#pragma unroll
        for (int n = 0; n < 4; ++n)
          acc[m][n] = __builtin_amdgcn_mfma_f32_16x16x32_bf16(af[m], bfr[n], acc[m][n], 0, 0, 0);
    }
    __syncthreads();
  }

  const int lr = (lane >> 4) << 2, lc = lane & 15;
#pragma unroll
  for (int m = 0; m < MR; ++m){
    const int grow0 = m0 + wr * (BM/2) + m * 16 + lr;
#pragma unroll
    for (int n = 0; n < 4; ++n){
      const int col = n0 + wc * 64 + n * 16 + lc;
      const float bv = bias[col];
#pragma unroll
      for (int r = 0; r < 4; ++r){
        const int grow = grow0 + r;
        float v = acc[m][n][r] + bv;
        if constexpr (EPI == 0){
          outB[(size_t)grow * ldo + col] = f2bf(0.5f * v * (1.f + erff(v * 0.70710678118654752f)));
        } else if constexpr (EPI == 1){
          outF[(size_t)grow * ldo + col] = v + ((const float*)res)[(size_t)grow * N + col];
        } else if constexpr (EPI == 2){
          outF[(size_t)grow * ldo + col] =
              (v + bf2f(((const u16*)res)[(size_t)grow * N + col])) * km[grow];
        } else {  // EPI 4
          const int rowout = grow & (MROWS - 1);
          const int coloff = (grow >> 13) << 9;
          outB[(size_t)rowout * ldo + coloff + col] =
              f2bf(v + ((const float*)res)[(size_t)rowout * N + col]);
        }
      }
    }
  }
}

// ---------------- 256x256-tile 8-phase GEMM (N multiple of 256) --------------
// EPI 0: bf16 out = gelu(v+bias); EPI 3: zgate silu*sigmoid (interleaved cols).
// 8 waves (wm=w>>2, wn=w&3), per-wave C = 128x64 (acc[8][4]).
template<int EPI>
__global__ __launch_bounds__(512, 1) void gemm256(
    const u16* __restrict__ A,
    const u16* __restrict__ BT0, const u16* __restrict__ BT1,
    const float* __restrict__ bias0, const float* __restrict__ bias1,
    u16* __restrict__ outB, int K, int N, int ldo, int nwg){
  extern __shared__ u16 lds[];   // [2 buf][2 op][256*64] = 128 KiB
  const int tid = threadIdx.x, w = tid >> 6, lane = tid & 63;
  int bid = (blockIdx.x & 7) * (nwg >> 3) + (blockIdx.x >> 3);  // XCD swizzle
  const int nbx = N >> 8;
  const int m0 = (bid / nbx) << 8, n0 = (bid % nbx) << 8;
  const u16* BT = (m0 < MROWS) ? BT0 : BT1;
  const float* bias = (m0 < MROWS) ? bias0 : bias1;
  const int wm = w >> 2, wn = w & 3;

  // staging: 512 threads x 16B = 64 rows/instr; 2 instrs per 128-row half
  const int srow = (w << 3) + (lane >> 3);
  const int scol = ((16 * (lane & 7)) ^ (((lane >> 3) & 7) << 4)) >> 1;
  const u16* gA = A + (size_t)(m0 + srow) * K + scol;
  const u16* gB = BT + (size_t)(n0 + srow) * K + scol;
  const int dstw = (w << 3) * 64;          // wave slice within half (u16)

  auto stA = [&](int b, int h, int kt){
    const u16* s = gA + (size_t)(h << 7) * K + (kt << 6);
    u16* d = &lds[((b << 1) + 0) * 16384 + (h << 7) * 64 + dstw];
    GLD16(s, d); GLD16(s + (size_t)64 * K, d + 64 * 64);
  };
  auto stB = [&](int b, int h, int kt){
    const u16* s = gB + (size_t)(h << 7) * K + (kt << 6);
    u16* d = &lds[((b << 1) + 1) * 16384 + (h << 7) * 64 + dstw];
    GLD16(s, d); GLD16(s + (size_t)64 * K, d + 64 * 64);
  };

  const int swz = (lane & 7) << 4;
  const int cb = (lane >> 4) << 4;
  const int fr = lane & 15;
  auto ldA = [&](int b, int mf, int ks)->bf16x8 {
    int row = (wm << 7) + (mf << 4) + fr;
    int byte = ((ks << 6) + cb) ^ swz;
    return *reinterpret_cast<const bf16x8*>(&lds[((b << 1) + 0) * 16384 + row * 64 + (byte >> 1)]);
  };
  auto ldB = [&](int b, int nf, int ks)->bf16x8 {
    int row = (wn << 6) + (nf << 4) + fr;
    int byte = ((ks << 6) + cb) ^ swz;
    return *reinterpret_cast<const bf16x8*>(&lds[((b << 1) + 1) * 16384 + row * 64 + (byte >> 1)]);
  };

  f32x4 acc[8][4] = {};
  bf16x8 aA[8], bB[2][4];
  const int nt2 = K >> 7;                   // iterations; 2 K-tiles each

  // prologue: ktile0 full -> b0; ktile1 B halves -> b1 (A halves land P1/P2)
  stA(0,0,0); stA(0,1,0); stB(0,0,0); stB(0,1,0);
  stB(1,0,1); stB(1,1,1);
  VMW(4);
  BARRIER();

#pragma unroll 1
  for (int j = 0; j < nt2; ++j){
    const int kt1 = 2*j + 1;
    const bool more = (j + 1 < nt2);
    const int ktn0 = 2*j + 2, ktn1 = 2*j + 3;

#define PHASE_MFMA(MB, BH)                                              \
    BARRIER(); LGKM0();                                                 \
    __builtin_amdgcn_s_setprio(1);                                      \
    _Pragma("unroll")                                                   \
    for (int m = 0; m < 4; ++m)                                         \
      _Pragma("unroll")                                                 \
      for (int n = 0; n < 2; ++n){                                      \
        acc[(MB)*4+m][(BH)*2+n] = __builtin_amdgcn_mfma_f32_16x16x32_bf16( \
            aA[2*m],   bB[BH][2*n],   acc[(MB)*4+m][(BH)*2+n], 0,0,0);  \
        acc[(MB)*4+m][(BH)*2+n] = __builtin_amdgcn_mfma_f32_16x16x32_bf16( \
            aA[2*m+1], bB[BH][2*n+1], acc[(MB)*4+m][(BH)*2+n], 0,0,0);  \
      }                                                                 \
    __builtin_amdgcn_s_setprio(0)

    // ---- P1: read A(b0) mf0-3 + B(b0) nf0-1; stage Ah0(b1,kt1)
#pragma unroll
    for (int m = 0; m < 4; ++m){ aA[2*m] = ldA(0,m,0); aA[2*m+1] = ldA(0,m,1); }
#pragma unroll
    for (int n = 0; n < 2; ++n){ bB[0][2*n] = ldB(0,n,0); bB[0][2*n+1] = ldB(0,n,1); }
    stA(1,0,kt1);
    PHASE_MFMA(0,0);
    BARRIER();
    // ---- P2: read B(b0) nf2-3; stage Ah1(b1,kt1)
#pragma unroll
    for (int n = 0; n < 2; ++n){ bB[1][2*n] = ldB(0,n+2,0); bB[1][2*n+1] = ldB(0,n+2,1); }
    stA(1,1,kt1);
    PHASE_MFMA(0,1);
    BARRIER();
    // ---- P3: read A(b0) mf4-7; stage Bh0(b0,ktn0)
#pragma unroll
    for (int m = 0; m < 4; ++m){ aA[2*m] = ldA(0,m+4,0); aA[2*m+1] = ldA(0,m+4,1); }
    if (more) stB(0,0,ktn0);
    PHASE_MFMA(1,1);
    BARRIER();
    // ---- P4: stage Bh1(b0,ktn0); MFMA; vmcnt drains b1's 8 loads
    if (more) stB(0,1,ktn0);
    PHASE_MFMA(1,0);
    if (more) { VMW(4); } else { VMW(0); }
    BARRIER();
    // ---- P5: read A(b1) mf0-3 + B(b1) nf0-1; stage Ah0(b0,ktn0)
#pragma unroll
    for (int m = 0; m < 4; ++m){ aA[2*m] = ldA(1,m,0); aA[2*m+1] = ldA(1,m,1); }
#pragma unroll
    for (int n = 0; n < 2; ++n){ bB[0][2*n] = ldB(1,n,0); bB[0][2*n+1] = ldB(1,n,1); }
    if (more) stA(0,0,ktn0);
    PHASE_MFMA(0,0);
    BARRIER();
    // ---- P6: read B(b1) nf2-3; stage Ah1(b0,ktn0)
#pragma unroll
    for (int n = 0; n < 2; ++n){ bB[1][2*n] = ldB(1,n+2,0); bB[1][2*n+1] = ldB(1,n+2,1); }
    if (more) stA(0,1,ktn0);
    PHASE_MFMA(0,1);
    BARRIER();
    // ---- P7: read A(b1) mf4-7; stage Bh0(b1,ktn1)
#pragma unroll
    for (int m = 0; m < 4; ++m){ aA[2*m] = ldA(1,m+4,0); aA[2*m+1] = ldA(1,m+4,1); }
    if (more) stB(1,0,ktn1);
    PHASE_MFMA(1,1);
    BARRIER();
    // ---- P8: stage Bh1(b1,ktn1); MFMA; vmcnt drains b0's 8 loads
    if (more) stB(1,1,ktn1);
    PHASE_MFMA(1,0);
    VMW(4);
    BARRIER();
#undef PHASE_MFMA
  }

  // ---- epilogue ----
  const int lr = (lane >> 4) << 2, lc = lane & 15;
#pragma unroll
  for (int m = 0; m < 8; ++m){
    const int grow0 = m0 + (wm << 7) + m * 16 + lr;
    if constexpr (EPI == 3){
#pragma unroll
      for (int n = 0; n < 4; n += 2){
        const int zc = n0 + (wn << 6) + n * 16 + lc;
        const int bi = ((zc >> 5) << 4) + lc;
        const float bz = bias[bi], bg = bias[(N >> 1) + bi];
        const int ucol = ((n0 + (wn << 6)) >> 1) + (n << 3) + lc;
#pragma unroll
        for (int r = 0; r < 4; ++r){
          float z = acc[m][n][r] + bz;
          float g = acc[m][n + 1][r] + bg;
          outB[(size_t)(grow0 + r) * ldo + ucol] =
              f2bf((z / (1.f + expf(-z))) * (1.f / (1.f + expf(-g))));
        }
      }
    } else {
#pragma unroll
      for (int n = 0; n < 4; ++n){
        const int col = n0 + (wn << 6) + n * 16 + lc;
        const float bv = bias[col];
#pragma unroll
        for (int r = 0; r < 4; ++r){
          float v = acc[m][n][r] + bv;
          outB[(size_t)(grow0 + r) * ldo + col] =
              f2bf(0.5f * v * (1.f + erff(v * 0.70710678118654752f)));
        }
      }
    }
  }
}

// -----------------------------------------------------------------------------
extern "C" void kernel_launch(void* const* d_in, const int* in_sizes, int n_in,
                              void* d_out, int out_size, void* d_ws, size_t ws_size,
                              hipStream_t stream){
  (void)in_sizes; (void)n_in; (void)out_size; (void)ws_size;
  const float* s_in   = (const float*)d_in[0];
  const float* attn   = (const float*)d_in[1];
  const float* km     = (const float*)d_in[2];
  const float* se_w1  = (const float*)d_in[3];
  const float* se_b1  = (const float*)d_in[4];
  const float* se_w2  = (const float*)d_in[5];
  const float* se_b2  = (const float*)d_in[6];
  const float* png[2] = {(const float*)d_in[7],  (const float*)d_in[15]};
  const float* pnb[2] = {(const float*)d_in[8],  (const float*)d_in[16]};
  const float* ppiw[2]= {(const float*)d_in[9],  (const float*)d_in[17]};
  const float* ppib[2]= {(const float*)d_in[10], (const float*)d_in[18]};
  const float* ppow[2]= {(const float*)d_in[11], (const float*)d_in[19]};
  const float* ppob[2]= {(const float*)d_in[12], (const float*)d_in[20]};
  const float* pig[2] = {(const float*)d_in[13], (const float*)d_in[21]};
  const float* pibt[2]= {(const float*)d_in[14], (const float*)d_in[22]};
  const float* mrg_w  = (const float*)d_in[23];
  const float* mrg_b  = (const float*)d_in[24];
  const float* nrm_g  = (const float*)d_in[25];
  const float* nrm_b  = (const float*)d_in[26];
  const float* ffn_ng = (const float*)d_in[27];
  const float* ffn_nb = (const float*)d_in[28];
  const float* ffn_w1 = (const float*)d_in[29];
  const float* ffn_b1 = (const float*)d_in[30];
  const float* ffn_w2 = (const float*)d_in[31];
  const float* ffn_b2 = (const float*)d_in[32];
  float* out = (float*)d_out;

  char* ws = (char*)d_ws;
  size_t off = 0;
  auto alloc = [&](size_t bytes)->char*{
    char* p = ws + off; off += (bytes + 255) & ~(size_t)255; return p; };

  u16* w_sew1 = (u16*)alloc(512 * 192 * 2);
  u16* w_sew2 = (u16*)alloc(512 * 512 * 2);
  u16* w_piw[2][2]; u16* w_pow[2][2];
  for (int d = 0; d < 2; ++d)
    for (int i = 0; i < 2; ++i){
      w_piw[d][i] = (u16*)alloc(2048 * 512 * 2);
      w_pow[d][i] = (u16*)alloc(512 * 1024 * 2);
    }
  u16* w_mrg[2]; u16* w_ffn1[2]; u16* w_ffn2[2];
  for (int i = 0; i < 2; ++i){
    w_mrg[i]  = (u16*)alloc(512 * 1024 * 2);
    w_ffn1[i] = (u16*)alloc(2048 * 512 * 2);
    w_ffn2[i] = (u16*)alloc(512 * 2048 * 2);
  }
  u16*   enc  = (u16*)alloc((size_t)MROWS * 192 * 2);
  u16*   t1h2 = (u16*)alloc((size_t)MROWS * 512 * 2);
  float* sc   = (float*)alloc((size_t)MROWS * 512 * 4);
  u16*   hcat = (u16*)alloc((size_t)2 * MROWS * 512 * 2);
  char*  big  = alloc((size_t)MROWS * 2048 * 2);
  u16*   upre = (u16*)big;
  u16*   r2   = (u16*)big;
  u16*   t2   = (u16*)big;
  u16*   ubf  = (u16*)alloc((size_t)2 * MROWS * 1024 * 2);
  u16*   fbuf = (u16*)alloc((size_t)MROWS * 1024 * 2);
  u16*   s1   = (u16*)alloc((size_t)MROWS * 512 * 2);

  // ---- weight conversion: ONE kernel over 16 descriptors ----
  TPack pk; int base = 0, di = 0;
  auto push = [&](const float* src, u16* dst, int R, int Kpad, int C, int zg){
    TDesc& t = pk.d[di++];
    t.src = src; t.dst = dst; t.R = R; t.Kpad = Kpad; t.C = C; t.zgate = zg;
    t.nbx = C / 32; t.base = base;
    base += (C / 32) * (Kpad / 32);
  };
  push(se_w1, w_sew1, 129, 192, 512, 0);
  push(se_w2, w_sew2, 512, 512, 512, 0);
  for (int d = 0; d < 2; ++d)
    for (int i = 0; i < 2; ++i){
      push(ppiw[d] + (size_t)i*512*2048, w_piw[d][i], 512, 512, 2048, 1);
      push(ppow[d] + (size_t)i*1024*512, w_pow[d][i], 1024, 1024, 512, 0);
    }
  for (int i = 0; i < 2; ++i){
    push(mrg_w  + (size_t)i*1024*512, w_mrg[i],  1024, 1024, 512, 0);
    push(ffn_w1 + (size_t)i*512*2048, w_ffn1[i], 512, 512, 2048, 0);
    push(ffn_w2 + (size_t)i*2048*512, w_ffn2[i], 2048, 2048, 512, 0);
  }
  transpose_all<<<base, 256, 0, stream>>>(pk);

  // ---- spatial encoding ----
  stats_enc<<<MROWS, 256, 0, stream>>>(attn, enc);
  gemm_bt<0,64><<<dim3(4, 128), 256, 0, stream>>>(enc, w_sew1, w_sew1, se_b1, se_b1,
      nullptr, nullptr, t1h2, nullptr, 192, 512, 512);
  gemm_bt<1,64><<<dim3(4, 128), 256, 0, stream>>>(t1h2, w_sew2, w_sew2, se_b2, se_b2,
      s_in, sc, nullptr, nullptr, 512, 512, 512);

  // ---- layers ----
  for (int i = 0; i < 2; ++i){
    ln_dual<<<MROWS/4, 256, 0, stream>>>(sc, png[0]+i*512, pnb[0]+i*512,
        png[1]+i*512, pnb[1]+i*512, hcat, hcat + (size_t)MROWS*512);
    // stacked f/b zi + silu*sigmoid: [16384,512]@[512,2048] -> u [16384][1024]
    gemm256<3><<<512, 512, 131072, stream>>>(hcat,
        w_piw[0][i], w_piw[1][i], ppib[0]+(size_t)i*2048, ppib[1]+(size_t)i*2048,
        upre, 512, 2048, 1024, 512);
    ln1024<<<(2*MROWS)/4, 256, 0, stream>>>(upre,
        pig[0]+i*1024, pibt[0]+i*1024, pig[1]+i*1024, pibt[1]+i*1024, ubf);
    gemm_bt<4,64><<<dim3(4, 256), 256, 0, stream>>>(ubf,
        w_pow[0][i], w_pow[1][i], ppob[0]+i*512, ppob[1]+i*512,
        sc, nullptr, fbuf, nullptr, 1024, 512, 1024);
    gemm_bt<4,64><<<dim3(4, 128), 256, 0, stream>>>(fbuf,
        w_mrg[i], w_mrg[i], mrg_b+i*512, mrg_b+i*512,
        sc, nullptr, r2, nullptr, 1024, 512, 512);
    ln_double<<<MROWS/4, 256, 0, stream>>>(r2, nrm_g+i*512, nrm_b+i*512,
        ffn_ng+i*512, ffn_nb+i*512, s1, t1h2);
    gemm256<0><<<256, 512, 131072, stream>>>(t1h2,
        w_ffn1[i], w_ffn1[i], ffn_b1+i*2048, ffn_b1+i*2048,
        t2, 512, 2048, 2048, 256);
    gemm_bt<2,64><<<dim3(4, 128), 256, 0, stream>>>(t2,
        w_ffn2[i], w_ffn2[i], ffn_b2+i*512, ffn_b2+i*512,
        s1, (i == 1 ? out : sc), nullptr, km, 2048, 512, 512);
  }
}

// Round 7
// 777.821 us; speedup vs baseline: 1.0135x; 1.0135x over previous
//
#include <hip/hip_runtime.h>
#include <cstdint>
#include <cstddef>

// GraphMambaLayer on MI355X.
// R7: revert R6's gemm256 (8-phase 256^2 regressed at K=512: nt2=4 iters,
// 1 blk/CU -> prologue/epilogue exposed). Back to R5 structure; BM=128 GEMMs
// get __launch_bounds__(256,3) (allow 3 blk/CU regalloc target).
// R6: 788 us. R5: 754 us absmax 0.0625. R4: 832. R3: 928.

typedef unsigned short u16;
typedef __bf16 bf16x8 __attribute__((ext_vector_type(8)));
typedef float f32x4 __attribute__((ext_vector_type(4)));

#define MROWS 8192

__device__ __forceinline__ u16 f2bf(float f){
  unsigned u = __float_as_uint(f);
  u += 0x7FFFu + ((u >> 16) & 1u);           // RNE
  return (u16)(u >> 16);
}
__device__ __forceinline__ float bf2f(u16 v){
  return __uint_as_float((unsigned)v << 16);
}

__device__ __forceinline__ float wred64(float v){
#pragma unroll
  for (int o = 32; o > 0; o >>= 1) v += __shfl_xor(v, o, 64);
  return v;
}

#define GLD16(gp, lp) __builtin_amdgcn_global_load_lds( \
    (const __attribute__((address_space(1))) unsigned int*)(gp), \
    (__attribute__((address_space(3))) unsigned int*)(lp), 16, 0, 0)

// ---------------- merged weight transpose + bf16 convert ---------------------
struct TDesc { const float* src; u16* dst; int R, Kpad, C, zgate, nbx, base; };
struct TPack { TDesc d[16]; };

__global__ __launch_bounds__(256) void transpose_all(TPack p){
  int bid = blockIdx.x;
  TDesc dd = p.d[0];
#pragma unroll
  for (int i = 1; i < 16; ++i) if (bid >= p.d[i].base) dd = p.d[i];
  int lb = bid - dd.base;
  int bx = lb % dd.nbx, by = lb / dd.nbx;

  __shared__ float tile[32][33];
  int n0 = bx << 5, k0 = by << 5;
  int tx = threadIdx.x & 31, ty = threadIdx.x >> 5;
#pragma unroll
  for (int i = 0; i < 32; i += 8){
    int k = k0 + ty + i, n = n0 + tx;
    int oc = n;
    if (dd.zgate){ int g = n >> 5, sl = n & 31;
      oc = (sl < 16) ? (g << 4) + sl : (dd.C >> 1) + (g << 4) + sl - 16; }
    tile[ty + i][tx] = (k < dd.R) ? dd.src[(size_t)k * dd.C + oc] : 0.f;
  }
  __syncthreads();
#pragma unroll
  for (int i = 0; i < 32; i += 8){
    int n = n0 + ty + i, k = k0 + tx;
    dd.dst[(size_t)n * dd.Kpad + k] = f2bf(tile[tx][ty + i]);
  }
}

// ---------------- attn_maps moments -> sinusoidal encoding -------------------
__global__ __launch_bounds__(256) void stats_enc(
    const float* __restrict__ attn, u16* __restrict__ enc){
  int row = blockIdx.x;
  const float4* a4 = (const float4*)(attn + (size_t)row * 4096);
  int t = threadIdx.x;
  const float inv63 = 1.0f / 63.0f;
  float s0 = 0, sy = 0, sx = 0, sy2 = 0, sx2 = 0;
#pragma unroll
  for (int i = 0; i < 4; ++i){
    int c = t + 256 * i;
    float4 v = a4[c];
    int n = 4 * c;
#pragma unroll
    for (int e = 0; e < 4; ++e){
      float av = (&v.x)[e];
      int nn = n + e;
      float gy = (float)(nn >> 6) * inv63;
      float gx = (float)(nn & 63) * inv63;
      s0 += av; sy += av * gy; sx += av * gx;
      sy2 += av * gy * gy; sx2 += av * gx * gx;
    }
  }
  s0 = wred64(s0); sy = wred64(sy); sx = wred64(sx);
  sy2 = wred64(sy2); sx2 = wred64(sx2);
  __shared__ float red[4][5];
  __shared__ float outv[3];
  int wv = t >> 6, lane = t & 63;
  if (lane == 0){ red[wv][0]=s0; red[wv][1]=sy; red[wv][2]=sx; red[wv][3]=sy2; red[wv][4]=sx2; }
  __syncthreads();
  if (t == 0){
    float S=0, Ay=0, Ax=0, Ay2=0, Ax2=0;
    for (int w = 0; w < 4; ++w){ S+=red[w][0]; Ay+=red[w][1]; Ax+=red[w][2]; Ay2+=red[w][3]; Ax2+=red[w][4]; }
    float denom = S + 1e-8f;
    float cy = Ay / denom, cx = Ax / denom;
    float sp2 = (Ay2 - 2.f*cy*Ay + cy*cy*S + Ax2 - 2.f*cx*Ax + cx*cx*S) / denom;
    outv[0] = cy; outv[1] = cx; outv[2] = sqrtf(fmaxf(sp2, 0.f));
  }
  __syncthreads();
  if (t < 192){
    float cy = outv[0], cx = outv[1];
    float val = 0.f;
    if (t < 128){
      int j = t & 31;
      float fr = expf(-0.28782313662425572f * (float)j);   // ln(10000)/32
      float base = (t < 64) ? cy : cx;
      float ang = base * fr;
      val = ((t >> 5) & 1) ? cosf(ang) : sinf(ang);
    } else if (t == 128) val = outv[2];
    enc[(size_t)row * 192 + t] = f2bf(val);
  }
}

// ---------------- LayerNorm kernels (1 wave / row) ---------------------------
__global__ __launch_bounds__(256) void ln_dual(
    const float* __restrict__ x,
    const float* __restrict__ g1, const float* __restrict__ b1,
    const float* __restrict__ g2, const float* __restrict__ b2,
    u16* __restrict__ o1, u16* __restrict__ o2){
  int row = blockIdx.x * 4 + (threadIdx.x >> 6);
  int lane = threadIdx.x & 63, c = lane * 8;
  const float* xr = x + (size_t)row * 512 + c;
  float v[8];
  *(float4*)(v) = *(const float4*)(xr); *(float4*)(v+4) = *(const float4*)(xr+4);
  float s = 0.f;
#pragma unroll
  for (int j = 0; j < 8; ++j) s += v[j];
  float m = wred64(s) * (1.f/512.f);
  float q = 0.f;
#pragma unroll
  for (int j = 0; j < 8; ++j){ float d = v[j]-m; q += d*d; }
  float rstd = rsqrtf(wred64(q)*(1.f/512.f) + 1e-5f);
  float G1[8],B1[8],G2[8],B2[8];
  *(float4*)(G1)=*(const float4*)(g1+c); *(float4*)(G1+4)=*(const float4*)(g1+c+4);
  *(float4*)(B1)=*(const float4*)(b1+c); *(float4*)(B1+4)=*(const float4*)(b1+c+4);
  *(float4*)(G2)=*(const float4*)(g2+c); *(float4*)(G2+4)=*(const float4*)(g2+c+4);
  *(float4*)(B2)=*(const float4*)(b2+c); *(float4*)(B2+4)=*(const float4*)(b2+c+4);
  u16 u1[8] __attribute__((aligned(16)));
  u16 u2[8] __attribute__((aligned(16)));
#pragma unroll
  for (int j = 0; j < 8; ++j){
    float nv = (v[j]-m)*rstd;
    u1[j] = f2bf(nv*G1[j]+B1[j]);
    u2[j] = f2bf(nv*G2[j]+B2[j]);
  }
  *(uint4*)(o1 + (size_t)row*512 + c) = *(const uint4*)u1;
  *(uint4*)(o2 + (size_t)row*512 + c) = *(const uint4*)u2;
}

// bf16 in -> bf16 out LN over 1024; 16384 stacked rows, params per row-half
__global__ __launch_bounds__(256) void ln1024(
    const u16* __restrict__ x,
    const float* __restrict__ gf, const float* __restrict__ bfp,
    const float* __restrict__ gb, const float* __restrict__ bbp,
    u16* __restrict__ o){
  int row = blockIdx.x * 4 + (threadIdx.x >> 6);
  int lane = threadIdx.x & 63, c = lane * 16;
  const float* g = (row >> 13) ? gb : gf;
  const float* b = (row >> 13) ? bbp : bfp;
  const u16* xr = x + (size_t)row * 1024 + c;
  u16 raw[16] __attribute__((aligned(16)));
  *(uint4*)(raw)     = *(const uint4*)(xr);
  *(uint4*)(raw + 8) = *(const uint4*)(xr + 8);
  float v[16];
#pragma unroll
  for (int j = 0; j < 16; ++j) v[j] = bf2f(raw[j]);
  float s = 0.f;
#pragma unroll
  for (int j = 0; j < 16; ++j) s += v[j];
  float m = wred64(s) * (1.f/1024.f);
  float q = 0.f;
#pragma unroll
  for (int j = 0; j < 16; ++j){ float d = v[j]-m; q += d*d; }
  float rstd = rsqrtf(wred64(q)*(1.f/1024.f) + 1e-5f);
  float G[16], B[16];
#pragma unroll
  for (int i = 0; i < 4; ++i){
    *(float4*)(G + 4*i) = *(const float4*)(g + c + 4*i);
    *(float4*)(B + 4*i) = *(const float4*)(b + c + 4*i);
  }
  u16 u[16] __attribute__((aligned(16)));
#pragma unroll
  for (int j = 0; j < 16; ++j) u[j] = f2bf((v[j]-m)*rstd*G[j] + B[j]);
  *(uint4*)(o + (size_t)row*1024 + c)     = *(const uint4*)(u);
  *(uint4*)(o + (size_t)row*1024 + c + 8) = *(const uint4*)(u + 8);
}

// r2(bf16) -> s1 = LN(r2; ng,nb) (bf16), h2 = LN(s1; fg,fb) (bf16)
__global__ __launch_bounds__(256) void ln_double(
    const u16* __restrict__ x,
    const float* __restrict__ ng, const float* __restrict__ nb,
    const float* __restrict__ fg, const float* __restrict__ fbv,
    u16* __restrict__ s1, u16* __restrict__ h2){
  int row = blockIdx.x * 4 + (threadIdx.x >> 6);
  int lane = threadIdx.x & 63, c = lane * 8;
  const u16* xr = x + (size_t)row * 512 + c;
  u16 raw[8] __attribute__((aligned(16)));
  *(uint4*)(raw) = *(const uint4*)(xr);
  float v[8];
#pragma unroll
  for (int j = 0; j < 8; ++j) v[j] = bf2f(raw[j]);
  float s = 0.f;
#pragma unroll
  for (int j = 0; j < 8; ++j) s += v[j];
  float m = wred64(s) * (1.f/512.f);
  float q = 0.f;
#pragma unroll
  for (int j = 0; j < 8; ++j){ float d = v[j]-m; q += d*d; }
  float rstd = rsqrtf(wred64(q)*(1.f/512.f) + 1e-5f);
  float NG[8],NB[8],FG[8],FB[8];
  *(float4*)(NG)=*(const float4*)(ng+c); *(float4*)(NG+4)=*(const float4*)(ng+c+4);
  *(float4*)(NB)=*(const float4*)(nb+c); *(float4*)(NB+4)=*(const float4*)(nb+c+4);
  *(float4*)(FG)=*(const float4*)(fg+c); *(float4*)(FG+4)=*(const float4*)(fg+c+4);
  *(float4*)(FB)=*(const float4*)(fbv+c);*(float4*)(FB+4)=*(const float4*)(fbv+c+4);
  float w[8];
#pragma unroll
  for (int j = 0; j < 8; ++j) w[j] = (v[j]-m)*rstd*NG[j] + NB[j];
  u16 us[8] __attribute__((aligned(16)));
#pragma unroll
  for (int j = 0; j < 8; ++j) us[j] = f2bf(w[j]);
  *(uint4*)(s1 + (size_t)row*512 + c) = *(const uint4*)us;
  float s2 = 0.f;
#pragma unroll
  for (int j = 0; j < 8; ++j) s2 += w[j];
  float m2 = wred64(s2) * (1.f/512.f);
  float q2 = 0.f;
#pragma unroll
  for (int j = 0; j < 8; ++j){ float d = w[j]-m2; q2 += d*d; }
  float rstd2 = rsqrtf(wred64(q2)*(1.f/512.f) + 1e-5f);
  u16 u[8] __attribute__((aligned(16)));
#pragma unroll
  for (int j = 0; j < 8; ++j) u[j] = f2bf((w[j]-m2)*rstd2*FG[j] + FB[j]);
  *(uint4*)(h2 + (size_t)row*512 + c) = *(const uint4*)u;
}

// ---------------- bf16 MFMA GEMM, A[M,K] x BT[N,K]^T, fused epilogues --------
// Stacked-direction support: blocks with m0>=8192 use BT1/bias1.
// EPI 0: bf16 out = gelu(v+bias)                    (ldo = N)
// EPI 1: f32 out = v+bias+res_f32                   (ldo = N)
// EPI 2: f32 out = (v+bias+res_bf16)*km[row]        (ldo = N)
// EPI 3: bf16 out[N/2] = silu(z)*sigmoid(g); weight rows z/gate-interleaved in
//        16-wide groups; bias in ORIGINAL layout (z: [0,N/2), gate: +N/2)
// EPI 4: bf16 out[(row&8191)*ldo + (row>>13)*512 + col] = v+bias+res_f32
template<int EPI, int BM>
__global__ __launch_bounds__(256, (BM == 64) ? 4 : 3) void gemm_bt(
    const u16* __restrict__ A,
    const u16* __restrict__ BT0, const u16* __restrict__ BT1,
    const float* __restrict__ bias0, const float* __restrict__ bias1,
    const void* __restrict__ res,
    float* __restrict__ outF, u16* __restrict__ outB,
    const float* __restrict__ km,
    int K, int N, int ldo){
  constexpr int MR = BM / 32;
  __shared__ u16 Asm[BM * 64];
  __shared__ u16 Bsm[128 * 64];
  const int tid = threadIdx.x, wv = tid >> 6, lane = tid & 63;
  const int m0 = blockIdx.y * BM, n0 = blockIdx.x << 7;
  const int wr = wv >> 1, wc = wv & 1;
  const u16* BT = (m0 < MROWS) ? BT0 : BT1;
  const float* bias = (m0 < MROWS) ? bias0 : bias1;

  const int rowin = lane >> 3;
  const int ksrc = ((16 * (lane & 7)) ^ (rowin << 4)) >> 1;
  const int rA = wv * (BM / 4) + rowin;
  const int rB = (wv << 5) + rowin;
  const u16* gA = A + (size_t)(m0 + rA) * K + ksrc;
  const u16* gB = BT + (size_t)(n0 + rB) * K + ksrc;
  u16* ldsA = Asm + wv * (BM / 4) * 64;
  u16* ldsB = Bsm + (wv << 11);

  f32x4 acc[MR][4] = {};
  const int cbase = 16 * (lane >> 4);
  const int swz = (lane & 7) << 4;

  for (int kt = 0; kt < K; kt += 64){
#pragma unroll
    for (int it = 0; it < BM / 32; ++it)
      GLD16(gA + (size_t)it * 8 * K + kt, ldsA + it * 512);
#pragma unroll
    for (int it = 0; it < 4; ++it)
      GLD16(gB + (size_t)it * 8 * K + kt, ldsB + it * 512);
    __syncthreads();
#pragma unroll
    for (int ks = 0; ks < 64; ks += 32){
      const int cs = ((2 * ks + cbase) ^ swz) >> 1;
      bf16x8 af[MR], bfr[4];
#pragma unroll
      for (int m = 0; m < MR; ++m)
        af[m] = *reinterpret_cast<const bf16x8*>(&Asm[(wr*(BM/2) + m*16 + (lane & 15)) * 64 + cs]);
#pragma unroll
      for (int n = 0; n < 4; ++n)
        bfr[n] = *reinterpret_cast<const bf16x8*>(&Bsm[(wc*64 + n*16 + (lane & 15)) * 64 + cs]);
#pragma unroll
      for (int m = 0; m < MR; ++m)
#pragma unroll
        for (int n = 0; n < 4; ++n)
          acc[m][n] = __builtin_amdgcn_mfma_f32_16x16x32_bf16(af[m], bfr[n], acc[m][n], 0, 0, 0);
    }
    __syncthreads();
  }

  const int lr = (lane >> 4) << 2, lc = lane & 15;
#pragma unroll
  for (int m = 0; m < MR; ++m){
    const int grow0 = m0 + wr * (BM/2) + m * 16 + lr;
    if constexpr (EPI == 3){
#pragma unroll
      for (int n = 0; n < 4; n += 2){
        const int zc = n0 + wc * 64 + n * 16 + lc;
        const int bi = ((zc >> 5) << 4) + lc;          // original z-col
        const float bz = bias[bi], bg = bias[(N >> 1) + bi];
        const int ucol = ((n0 + wc * 64) >> 1) + (n << 3) + lc;
#pragma unroll
        for (int r = 0; r < 4; ++r){
          float z = acc[m][n][r] + bz;
          float g = acc[m][n + 1][r] + bg;
          outB[(size_t)(grow0 + r) * ldo + ucol] =
              f2bf((z / (1.f + expf(-z))) * (1.f / (1.f + expf(-g))));
        }
      }
    } else {
#pragma unroll
      for (int n = 0; n < 4; ++n){
        const int col = n0 + wc * 64 + n * 16 + lc;
        const float bv = bias[col];
#pragma unroll
        for (int r = 0; r < 4; ++r){
          const int grow = grow0 + r;
          float v = acc[m][n][r] + bv;
          if constexpr (EPI == 0){
            outB[(size_t)grow * ldo + col] = f2bf(0.5f * v * (1.f + erff(v * 0.70710678118654752f)));
          } else if constexpr (EPI == 1){
            outF[(size_t)grow * ldo + col] = v + ((const float*)res)[(size_t)grow * N + col];
          } else if constexpr (EPI == 2){
            outF[(size_t)grow * ldo + col] =
                (v + bf2f(((const u16*)res)[(size_t)grow * N + col])) * km[grow];
          } else {  // EPI 4
            const int rowout = grow & (MROWS - 1);
            const int coloff = (grow >> 13) << 9;
            outB[(size_t)rowout * ldo + coloff + col] =
                f2bf(v + ((const float*)res)[(size_t)rowout * N + col]);
          }
        }
      }
    }
  }
}

// -----------------------------------------------------------------------------
extern "C" void kernel_launch(void* const* d_in, const int* in_sizes, int n_in,
                              void* d_out, int out_size, void* d_ws, size_t ws_size,
                              hipStream_t stream){
  (void)in_sizes; (void)n_in; (void)out_size; (void)ws_size;
  const float* s_in   = (const float*)d_in[0];
  const float* attn   = (const float*)d_in[1];
  const float* km     = (const float*)d_in[2];
  const float* se_w1  = (const float*)d_in[3];
  const float* se_b1  = (const float*)d_in[4];
  const float* se_w2  = (const float*)d_in[5];
  const float* se_b2  = (const float*)d_in[6];
  const float* png[2] = {(const float*)d_in[7],  (const float*)d_in[15]};
  const float* pnb[2] = {(const float*)d_in[8],  (const float*)d_in[16]};
  const float* ppiw[2]= {(const float*)d_in[9],  (const float*)d_in[17]};
  const float* ppib[2]= {(const float*)d_in[10], (const float*)d_in[18]};
  const float* ppow[2]= {(const float*)d_in[11], (const float*)d_in[19]};
  const float* ppob[2]= {(const float*)d_in[12], (const float*)d_in[20]};
  const float* pig[2] = {(const float*)d_in[13], (const float*)d_in[21]};
  const float* pibt[2]= {(const float*)d_in[14], (const float*)d_in[22]};
  const float* mrg_w  = (const float*)d_in[23];
  const float* mrg_b  = (const float*)d_in[24];
  const float* nrm_g  = (const float*)d_in[25];
  const float* nrm_b  = (const float*)d_in[26];
  const float* ffn_ng = (const float*)d_in[27];
  const float* ffn_nb = (const float*)d_in[28];
  const float* ffn_w1 = (const float*)d_in[29];
  const float* ffn_b1 = (const float*)d_in[30];
  const float* ffn_w2 = (const float*)d_in[31];
  const float* ffn_b2 = (const float*)d_in[32];
  float* out = (float*)d_out;

  char* ws = (char*)d_ws;
  size_t off = 0;
  auto alloc = [&](size_t bytes)->char*{
    char* p = ws + off; off += (bytes + 255) & ~(size_t)255; return p; };

  u16* w_sew1 = (u16*)alloc(512 * 192 * 2);
  u16* w_sew2 = (u16*)alloc(512 * 512 * 2);
  u16* w_piw[2][2]; u16* w_pow[2][2];
  for (int d = 0; d < 2; ++d)
    for (int i = 0; i < 2; ++i){
      w_piw[d][i] = (u16*)alloc(2048 * 512 * 2);
      w_pow[d][i] = (u16*)alloc(512 * 1024 * 2);
    }
  u16* w_mrg[2]; u16* w_ffn1[2]; u16* w_ffn2[2];
  for (int i = 0; i < 2; ++i){
    w_mrg[i]  = (u16*)alloc(512 * 1024 * 2);
    w_ffn1[i] = (u16*)alloc(2048 * 512 * 2);
    w_ffn2[i] = (u16*)alloc(512 * 2048 * 2);
  }
  u16*   enc  = (u16*)alloc((size_t)MROWS * 192 * 2);
  u16*   t1h2 = (u16*)alloc((size_t)MROWS * 512 * 2);
  float* sc   = (float*)alloc((size_t)MROWS * 512 * 4);
  u16*   hcat = (u16*)alloc((size_t)2 * MROWS * 512 * 2);
  char*  big  = alloc((size_t)MROWS * 2048 * 2);
  u16*   upre = (u16*)big;
  u16*   r2   = (u16*)big;
  u16*   t2   = (u16*)big;
  u16*   ubf  = (u16*)alloc((size_t)2 * MROWS * 1024 * 2);
  u16*   fbuf = (u16*)alloc((size_t)MROWS * 1024 * 2);
  u16*   s1   = (u16*)alloc((size_t)MROWS * 512 * 2);

  // ---- weight conversion: ONE kernel over 16 descriptors ----
  TPack pk; int base = 0, di = 0;
  auto push = [&](const float* src, u16* dst, int R, int Kpad, int C, int zg){
    TDesc& t = pk.d[di++];
    t.src = src; t.dst = dst; t.R = R; t.Kpad = Kpad; t.C = C; t.zgate = zg;
    t.nbx = C / 32; t.base = base;
    base += (C / 32) * (Kpad / 32);
  };
  push(se_w1, w_sew1, 129, 192, 512, 0);
  push(se_w2, w_sew2, 512, 512, 512, 0);
  for (int d = 0; d < 2; ++d)
    for (int i = 0; i < 2; ++i){
      push(ppiw[d] + (size_t)i*512*2048, w_piw[d][i], 512, 512, 2048, 1);
      push(ppow[d] + (size_t)i*1024*512, w_pow[d][i], 1024, 1024, 512, 0);
    }
  for (int i = 0; i < 2; ++i){
    push(mrg_w  + (size_t)i*1024*512, w_mrg[i],  1024, 1024, 512, 0);
    push(ffn_w1 + (size_t)i*512*2048, w_ffn1[i], 512, 512, 2048, 0);
    push(ffn_w2 + (size_t)i*2048*512, w_ffn2[i], 2048, 2048, 512, 0);
  }
  transpose_all<<<base, 256, 0, stream>>>(pk);

  // ---- spatial encoding ----
  stats_enc<<<MROWS, 256, 0, stream>>>(attn, enc);
  gemm_bt<0,64><<<dim3(4, 128), 256, 0, stream>>>(enc, w_sew1, w_sew1, se_b1, se_b1,
      nullptr, nullptr, t1h2, nullptr, 192, 512, 512);
  gemm_bt<1,64><<<dim3(4, 128), 256, 0, stream>>>(t1h2, w_sew2, w_sew2, se_b2, se_b2,
      s_in, sc, nullptr, nullptr, 512, 512, 512);

  // ---- layers (order/rv/flip cancel: all per-token) ----
  for (int i = 0; i < 2; ++i){
    ln_dual<<<MROWS/4, 256, 0, stream>>>(sc, png[0]+i*512, pnb[0]+i*512,
        png[1]+i*512, pnb[1]+i*512, hcat, hcat + (size_t)MROWS*512);
    // stacked f/b zi + silu*sigmoid: [16384,512]@[512,2048] -> u [16384][1024]
    gemm_bt<3,128><<<dim3(16, 128), 256, 0, stream>>>(hcat,
        w_piw[0][i], w_piw[1][i], ppib[0]+(size_t)i*2048, ppib[1]+(size_t)i*2048,
        nullptr, nullptr, upre, nullptr, 512, 2048, 1024);
    ln1024<<<(2*MROWS)/4, 256, 0, stream>>>(upre,
        pig[0]+i*1024, pibt[0]+i*1024, pig[1]+i*1024, pibt[1]+i*1024, ubf);
    gemm_bt<4,64><<<dim3(4, 256), 256, 0, stream>>>(ubf,
        w_pow[0][i], w_pow[1][i], ppob[0]+i*512, ppob[1]+i*512,
        sc, nullptr, fbuf, nullptr, 1024, 512, 1024);
    gemm_bt<4,64><<<dim3(4, 128), 256, 0, stream>>>(fbuf,
        w_mrg[i], w_mrg[i], mrg_b+i*512, mrg_b+i*512,
        sc, nullptr, r2, nullptr, 1024, 512, 512);
    ln_double<<<MROWS/4, 256, 0, stream>>>(r2, nrm_g+i*512, nrm_b+i*512,
        ffn_ng+i*512, ffn_nb+i*512, s1, t1h2);
    gemm_bt<0,128><<<dim3(16, 64), 256, 0, stream>>>(t1h2,
        w_ffn1[i], w_ffn1[i], ffn_b1+i*2048, ffn_b1+i*2048,
        nullptr, nullptr, t2, nullptr, 512, 2048, 2048);
    gemm_bt<2,64><<<dim3(4, 128), 256, 0, stream>>>(t2,
        w_ffn2[i], w_ffn2[i], ffn_b2+i*512, ffn_b2+i*512,
        s1, (i == 1 ? out : sc), nullptr, km, 2048, 512, 512);
  }
}